// Round 2
// baseline (126.754 us; speedup 1.0000x reference)
//
#include <hip/hip_runtime.h>
#include <stdint.h>

typedef float  f32x4 __attribute__((ext_vector_type(4)));
typedef short  s16x8 __attribute__((ext_vector_type(8)));
typedef unsigned short u16x4 __attribute__((ext_vector_type(4)));

constexpr int D      = 64;     // feature dim (fixed by problem)
constexpr int SPLITS = 32;     // M-dimension chunks (grid.x)
constexpr int TILE_M = 128;    // targets staged in LDS per tile
constexpr int ROWS_B = 256;    // source rows per block (R=4 groups of 64)

__device__ __forceinline__ unsigned short f2bf(float f) {
    unsigned int u = __float_as_uint(f);
    u = (u + 0x7FFFu + ((u >> 16) & 1u)) >> 16;
    return (unsigned short)u;
}

// async 16B global->LDS; dest must be wave-uniform base (HW writes base + lane*16)
__device__ __forceinline__ void gld_lds16(const void* g, void* l) {
    __builtin_amdgcn_global_load_lds(
        (const __attribute__((address_space(1))) unsigned int*)(uintptr_t)g,
        (__attribute__((address_space(3))) unsigned int*)(uintptr_t)(unsigned)(uintptr_t)l,
        16, 0, 0);
}

// ---- prep: Yb = bf16(-2*y); t[m] = ||y||^2 - psi[m]; psum += block's psi sum
// block=256thr -> 16 rows; lane L: row sub=L>>4, 4 floats at col (L&15)*4
__global__ void prep_targets(const float* __restrict__ Y,
                             const float* __restrict__ psi,
                             unsigned short* __restrict__ Yb,
                             float* __restrict__ t,
                             float* __restrict__ psum) {
    const int tid  = threadIdx.x;
    const int lane = tid & 63;
    const int wave = tid >> 6;
    const int sub  = lane >> 4;
    const int l16  = lane & 15;
    const int row  = blockIdx.x * 16 + wave * 4 + sub;

    const float4 v = *reinterpret_cast<const float4*>(Y + row * D + l16 * 4);
    u16x4 o;
    o[0] = f2bf(-2.f * v.x); o[1] = f2bf(-2.f * v.y);
    o[2] = f2bf(-2.f * v.z); o[3] = f2bf(-2.f * v.w);
    *reinterpret_cast<u16x4*>(Yb + row * D + l16 * 4) = o;

    float s = v.x * v.x + v.y * v.y + v.z * v.z + v.w * v.w;
    #pragma unroll
    for (int off = 1; off <= 8; off <<= 1) s += __shfl_xor(s, off);

    float p = 0.f;
    if (l16 == 0) { p = psi[row]; t[row] = s - p; }
    p += __shfl_xor(p, 16);
    p += __shfl_xor(p, 32);

    __shared__ float ps[4];
    if (lane == 0) ps[wave] = p;
    __syncthreads();
    if (tid == 0) atomicAdd(psum, ps[0] + ps[1] + ps[2] + ps[3]);
}

// ---- main: fused bf16-MFMA + running-min. grid=(SPLITS, N/ROWS_B), block=256.
// acc init = t[m] (per-col), Yb pre-scaled by -2 -> acc = ||y||^2-psi-2<x,y>.
__global__ __launch_bounds__(256, 4)
void sdot_main(const float* __restrict__ X,
               const unsigned short* __restrict__ Yb,
               const float* __restrict__ t,
               float* __restrict__ partial,
               int M, int N) {
    __shared__ __align__(16) unsigned short ly[TILE_M * D];
    __shared__ float lt[TILE_M];

    const int tid  = threadIdx.x;
    const int wave = tid >> 6;
    const int lane = tid & 63;
    const int quad = lane >> 4;
    const int r16  = lane & 15;
    const int chunk   = blockIdx.x;
    const int rowgrp  = blockIdx.y;
    const int CH      = M / SPLITS;
    const int m_begin = chunk * CH;

    // A-frags: 4 groups x 2 K-halves; A[m=lane&15][k=quad*8+j]
    s16x8 a[4][2];
    #pragma unroll
    for (int g = 0; g < 4; g++) {
        const int srow = rowgrp * ROWS_B + g * 64 + wave * 16 + r16;
        #pragma unroll
        for (int h = 0; h < 2; h++) {
            const float4 u0 = *reinterpret_cast<const float4*>(X + srow * D + h * 32 + quad * 8);
            const float4 u1 = *reinterpret_cast<const float4*>(X + srow * D + h * 32 + quad * 8 + 4);
            s16x8 fr;
            fr[0] = (short)f2bf(u0.x); fr[1] = (short)f2bf(u0.y);
            fr[2] = (short)f2bf(u0.z); fr[3] = (short)f2bf(u0.w);
            fr[4] = (short)f2bf(u1.x); fr[5] = (short)f2bf(u1.y);
            fr[6] = (short)f2bf(u1.z); fr[7] = (short)f2bf(u1.w);
            a[g][h] = fr;
        }
    }

    float rmin[4][4];
    #pragma unroll
    for (int g = 0; g < 4; g++)
        #pragma unroll
        for (int r = 0; r < 4; r++) rmin[g][r] = 1e30f;

    for (int mb = m_begin; mb < m_begin + CH; mb += TILE_M) {
        __syncthreads();
        // stage 128x64 bf16 (16KB): linear LDS dest, XOR-swizzled source pick.
        // dest granule d = i*256+tid; holds logical chunk c = (d&7)^(row&7) of row d>>3
        #pragma unroll
        for (int i = 0; i < 4; i++) {
            const int d   = i * 256 + tid;
            const int row = d >> 3;
            const int c   = (d & 7) ^ (row & 7);
            gld_lds16(Yb + (size_t)(mb + row) * D + c * 8,
                      &ly[(size_t)(i * 256 + wave * 64) * 8]);
        }
        if (tid < TILE_M) lt[tid] = t[mb + tid];
        __syncthreads();

        #pragma unroll
        for (int st = 0; st < TILE_M / 16; st++) {
            const int trow = st * 16 + r16;      // B[n=lane&15][k=quad*8+j]
            const int sw   = trow & 7;
            const s16x8 b0 = *reinterpret_cast<const s16x8*>(&ly[trow * D + ((quad    ) ^ sw) * 8]);
            const s16x8 b1 = *reinterpret_cast<const s16x8*>(&ly[trow * D + ((quad + 4) ^ sw) * 8]);
            const float tv = lt[trow];
            #pragma unroll
            for (int g = 0; g < 4; g++) {
                f32x4 acc = {tv, tv, tv, tv};
                acc = __builtin_amdgcn_mfma_f32_16x16x32_bf16(a[g][0], b0, acc, 0, 0, 0);
                acc = __builtin_amdgcn_mfma_f32_16x16x32_bf16(a[g][1], b1, acc, 0, 0, 0);
                #pragma unroll
                for (int r = 0; r < 4; r++)
                    rmin[g][r] = fminf(rmin[g][r], acc[r]);
            }
        }
    }

    // min across the 16 columns (targets) of each quad
    #pragma unroll
    for (int off = 1; off <= 8; off <<= 1)
        #pragma unroll
        for (int g = 0; g < 4; g++)
            #pragma unroll
            for (int r = 0; r < 4; r++)
                rmin[g][r] = fminf(rmin[g][r], __shfl_xor(rmin[g][r], off));

    if (r16 == 0) {
        #pragma unroll
        for (int g = 0; g < 4; g++) {
            const int rowbase = rowgrp * ROWS_B + g * 64 + wave * 16 + quad * 4;
            #pragma unroll
            for (int r = 0; r < 4; r++)
                partial[(size_t)chunk * N + rowbase + r] = rmin[g][r];   // coalesced per block
        }
    }
}

// ---- finalize: out[n] = ||x_n||^2 + psum/M + min over SPLITS partials
__global__ void finalize(const float* __restrict__ X,
                         const float* __restrict__ partial,
                         const float* __restrict__ psum,
                         float* __restrict__ out, int N, float invM) {
    const int lane = threadIdx.x & 63;
    const int wave = threadIdx.x >> 6;
    const int row  = blockIdx.x * 4 + wave;
    const float x = X[row * D + lane];
    float s = x * x;
    #pragma unroll
    for (int off = 1; off <= 32; off <<= 1) s += __shfl_xor(s, off);
    float pm = (lane < SPLITS) ? partial[(size_t)lane * N + row] : 1e30f;
    #pragma unroll
    for (int off = 1; off <= 32; off <<= 1) pm = fminf(pm, __shfl_xor(pm, off));
    if (lane == 0) out[row] = s + pm + psum[0] * invM;
}

extern "C" void kernel_launch(void* const* d_in, const int* in_sizes, int n_in,
                              void* d_out, int out_size, void* d_ws, size_t ws_size,
                              hipStream_t stream) {
    const float* X   = (const float*)d_in[0];   // [N, 64]
    const float* Y   = (const float*)d_in[1];   // [M, 64]
    const float* psi = (const float*)d_in[2];   // [M]
    float* out = (float*)d_out;

    const int N = in_sizes[0] / D;   // 8192
    const int M = in_sizes[2];       // 32768

    char* ws = (char*)d_ws;
    unsigned short* Yb = (unsigned short*)ws;                 // M*64 bf16  (4 MB)
    size_t off = (size_t)M * D * sizeof(unsigned short);
    float* t = (float*)(ws + off);                            // M floats   (128 KB)
    off += (size_t)M * sizeof(float);
    float* partial = (float*)(ws + off);                      // SPLITS*N   (1 MB)
    off += (size_t)SPLITS * N * sizeof(float);
    float* psum = (float*)(ws + off);                         // 1 float

    hipMemsetAsync(psum, 0, sizeof(float), stream);
    prep_targets<<<M / 16, 256, 0, stream>>>(Y, psi, Yb, t, psum);
    dim3 grid(SPLITS, N / ROWS_B);
    sdot_main<<<grid, 256, 0, stream>>>(X, Yb, t, partial, M, N);
    finalize<<<N / 4, 256, 0, stream>>>(X, partial, psum, out, N, 1.0f / (float)M);
}